// Round 1
// 2693.193 us; speedup vs baseline: 1.1386x; 1.1386x over previous
//
#include <hip/hip_runtime.h>
#include <hip/hip_bf16.h>

typedef __hip_bfloat16 bf16;

#define BN_EPS 1e-5f

// ---- dtype-adaptive load/store: FP32=true -> float*, false -> bf16* ----
template<bool FP32>
__device__ __forceinline__ float ld(const void* p, long i) {
    if constexpr (FP32) return ((const float*)p)[i];
    else                return (float)((const bf16*)p)[i];
}
template<bool FP32>
__device__ __forceinline__ void st(void* p, long i, float v) {
    if constexpr (FP32) ((float*)p)[i] = v;
    else                ((bf16*)p)[i] = (bf16)v;
}

// ---------------- dtype probe ----------------
__global__ void dtype_probe_kernel(const unsigned short* __restrict__ y, int* __restrict__ flag)
{
    int tid = threadIdx.x;  // 64 threads
    int mx = 0;
    for (int i = tid; i < 4096; i += 64) {
        int e = (y[i] >> 7) & 0xFF;
        mx = max(mx, e);
    }
    #pragma unroll
    for (int off = 32; off > 0; off >>= 1)
        mx = max(mx, __shfl_down(mx, off, 64));
    if (tid == 0) *flag = (mx >= 141) ? 1 : 0;
}

// ---------------- fused MLP: f -> memory_filters, g, h ----------------
// grid = 13 blocks (one per slot), 256 threads.
template<bool FP32>
__global__ __launch_bounds__(256) void mlp_kernel(
    const void* __restrict__ w1, const void* __restrict__ b1,
    const void* __restrict__ w2, const void* __restrict__ b2,
    const void* __restrict__ w3, const void* __restrict__ b3,
    const void* __restrict__ c2w, const void* __restrict__ c2b,
    void* __restrict__ d_out,          // memory_filters at offset 0
    float* __restrict__ g_out,         // 13*32
    float* __restrict__ h_out,         // 13
    const int* __restrict__ flag)
{
    if (*flag != (FP32 ? 1 : 0)) return;

    __shared__ float f1[1024];
    __shared__ float f2[2048];
    __shared__ float f3[96];
    __shared__ float fn[96];
    __shared__ float inv_s;

    int s   = blockIdx.x;
    int tid = threadIdx.x;

    // f1 = relu(w1[s,:] + b1)
    for (int j = tid; j < 1024; j += 256)
        f1[j] = fmaxf(ld<FP32>(w1, s * 1024 + j) + ld<FP32>(b1, j), 0.f);
    __syncthreads();

    // f2 = relu(f1 @ w2 + b2), 8 outputs per thread, j-outer for ILP
    {
        float acc[8];
        #pragma unroll
        for (int i = 0; i < 8; ++i) acc[i] = ld<FP32>(b2, tid + 256 * i);
        for (int j = 0; j < 1024; ++j) {
            float a = f1[j];
            long base = (long)j * 2048 + tid;
            #pragma unroll
            for (int i = 0; i < 8; ++i)
                acc[i] = fmaf(a, ld<FP32>(w2, base + 256 * i), acc[i]);
        }
        #pragma unroll
        for (int i = 0; i < 8; ++i) f2[tid + 256 * i] = fmaxf(acc[i], 0.f);
    }
    __syncthreads();

    // f3 = f2 @ w3 + b3 (96 outputs; 4 partial accumulators for ILP)
    if (tid < 96) {
        float a0 = 0.f, a1 = 0.f, a2 = 0.f, a3 = 0.f;
        for (int k = 0; k < 2048; k += 4) {
            a0 = fmaf(f2[k],     ld<FP32>(w3, (long)(k)     * 96 + tid), a0);
            a1 = fmaf(f2[k + 1], ld<FP32>(w3, (long)(k + 1) * 96 + tid), a1);
            a2 = fmaf(f2[k + 2], ld<FP32>(w3, (long)(k + 2) * 96 + tid), a2);
            a3 = fmaf(f2[k + 3], ld<FP32>(w3, (long)(k + 3) * 96 + tid), a3);
        }
        f3[tid] = ld<FP32>(b3, tid) + ((a0 + a1) + (a2 + a3));
    }
    __syncthreads();

    if (tid == 0) {
        float ss = 0.f;
        for (int c = 0; c < 96; ++c) ss += f3[c] * f3[c];
        inv_s = 1.f / fmaxf(sqrtf(ss), 1e-12f);
    }
    __syncthreads();

    if (tid < 96) {
        float v = f3[tid] * inv_s;
        fn[tid] = v;
        st<FP32>(d_out, s * 96 + tid, v);   // memory_filters
    }
    __syncthreads();

    // g[s,c] = sum_o fn[o] * conv2_w[o,c];  h[s] = sum_o fn[o] * conv2_b[o]
    if (tid < 32) {
        float g = 0.f;
        #pragma unroll
        for (int o = 0; o < 96; ++o) g = fmaf(fn[o], ld<FP32>(c2w, o * 32 + tid), g);
        g_out[s * 32 + tid] = g;
    } else if (tid == 64) {
        float hv = 0.f;
        for (int o = 0; o < 96; ++o) hv = fmaf(fn[o], ld<FP32>(c2b, o), hv);
        h_out[s] = hv;
    }
}

// ---------------- fused conv1 + BN + PReLU + (g,h) projection -> logits ----------------
// grid = 2*96*96 blocks (one per (b,h,w) row of 96 d), 256 threads.
// Thread map: ocg = tid&15 -> owns oc = ocg and ocg+16;  dg = tid>>4 -> 6 consecutive d.
// ic processed in 8 chunks of 4; y rows + weights for the chunk staged in LDS.
// LDS ~43.5 KB -> 3 blocks/CU (12 waves); launch_bounds(256,3) allows ~168 VGPR.
template<bool FP32>
__global__ __launch_bounds__(256, 3) void conv_fused_kernel(
    const void* __restrict__ y, const void* __restrict__ w1c, const void* __restrict__ b1c,
    const void* __restrict__ gamma, const void* __restrict__ beta,
    const void* __restrict__ mean,  const void* __restrict__ var,
    const void* __restrict__ alpha_p,
    const float* __restrict__ g_in, const float* __restrict__ h_in,
    void* __restrict__ d_out,
    const int* __restrict__ flag)
{
    if (*flag != (FP32 ? 1 : 0)) return;

    __shared__ float y_tile[36 * 98];      // rows r = dzdy*4 + icl, 98 d (zero halo)
    __shared__ float w_tile[4 * 32 * 28];  // [icl][oc][27] padded to 28
    __shared__ float t_tile[32 * 97];      // [oc][d] +1 pad
    __shared__ float g_sh[13 * 32];
    __shared__ float h_sh[13];
    __shared__ float bninv[32], bnbias[32], cb[32];
    __shared__ float alpha_sh;
    __shared__ int   row_goff[36];         // per-row global element offset (excl. batch/ch)
    __shared__ int   row_ok[36];           // (hh2,ww2) in-bounds

    int tid = threadIdx.x;
    int bid = blockIdx.x;
    int b   = bid / 9216;
    int rem = bid - b * 9216;
    int h   = rem / 96;
    int w   = rem - h * 96;

    for (int j = tid; j < 13 * 32; j += 256) g_sh[j] = g_in[j];
    if (tid < 13) h_sh[tid] = h_in[tid];
    if (tid >= 32 && tid < 64) {
        int c = tid - 32;
        float iv = ld<FP32>(gamma, c) * rsqrtf(ld<FP32>(var, c) + BN_EPS);
        bninv[c]  = iv;
        bnbias[c] = ld<FP32>(beta, c) - ld<FP32>(mean, c) * iv;
        cb[c]     = ld<FP32>(b1c, c);
    }
    if (tid == 64) alpha_sh = ld<FP32>(alpha_p, 0);
    if (tid < 36) {
        int dzdy = tid >> 2, icl = tid & 3;
        int dz = dzdy / 3, dy = dzdy - dz * 3;
        int hh2 = h + dz - 1, ww2 = w + dy - 1;
        row_ok[tid]   = ((unsigned)hh2 < 96u) && ((unsigned)ww2 < 96u);
        row_goff[tid] = icl * 884736 + hh2 * 9216 + ww2 * 96;
    }

    int ocg = tid & 15;     // owns oc = ocg, ocg+16
    int dg  = tid >> 4;     // 16 groups of 6 d
    int D0  = dg * 6;
    int wv  = tid >> 6;     // wave id 0..3
    int ln  = tid & 63;     // lane

    float accA[6], accB[6];
    #pragma unroll
    for (int i = 0; i < 6; ++i) { accA[i] = 0.f; accB[i] = 0.f; }

    #pragma unroll 1
    for (int ch = 0; ch < 8; ++ch) {
        __syncthreads();

        // ---- stage y rows: wave per row, lanes cover 98 positions (pos = dd+1) ----
        int bbase = (b * 32 + ch * 4) * 884736;
        for (int r = wv; r < 36; r += 4) {
            float* dst = &y_tile[r * 98];
            if (row_ok[r]) {
                int base = bbase + row_goff[r];
                dst[ln] = (ln >= 1) ? ld<FP32>(y, base + (ln - 1)) : 0.f;
                if (ln < 34)
                    dst[ln + 64] = (ln <= 32) ? ld<FP32>(y, base + (ln + 63)) : 0.f;
            } else {
                dst[ln] = 0.f;
                if (ln < 34) dst[ln + 64] = 0.f;
            }
        }

        // ---- stage weights for this 4-ic chunk: 2 threads per (icl,oc) row of 27 ----
        {
            int p    = tid >> 1;          // 0..127 = (icl,oc)
            int half = tid & 1;
            int icl  = p >> 5;
            int oc   = p & 31;
            int t0   = half ? 14 : 0;
            int n    = half ? 13 : 14;
            int gb   = (oc * 32 + (ch * 4 + icl)) * 27 + t0;
            float* dw = &w_tile[(icl * 32 + oc) * 28 + t0];
            for (int q = 0; q < n; ++q) dw[q] = ld<FP32>(w1c, gb + q);
        }
        __syncthreads();

        // ---- compute: 4 ic x 9 (dz,dy) x 3 d-taps x 6 d x 2 oc ----
        #pragma unroll
        for (int icl = 0; icl < 4; ++icl) {
            const float* wp = &w_tile[(icl * 32 + ocg) * 28];
            float wA[27], wB[27];
            #pragma unroll
            for (int t = 0; t < 27; ++t) { wA[t] = wp[t]; wB[t] = wp[16 * 28 + t]; }
            #pragma unroll
            for (int dzdy = 0; dzdy < 9; ++dzdy) {
                const float* row = &y_tile[(dzdy * 4 + icl) * 98 + D0];
                float r8[8];
                #pragma unroll
                for (int q = 0; q < 8; ++q) r8[q] = row[q];
                float a0 = wA[dzdy * 3], a1 = wA[dzdy * 3 + 1], a2 = wA[dzdy * 3 + 2];
                float b0 = wB[dzdy * 3], b1 = wB[dzdy * 3 + 1], b2 = wB[dzdy * 3 + 2];
                #pragma unroll
                for (int i = 0; i < 6; ++i) {
                    accA[i] = fmaf(a0, r8[i],     accA[i]);
                    accA[i] = fmaf(a1, r8[i + 1], accA[i]);
                    accA[i] = fmaf(a2, r8[i + 2], accA[i]);
                    accB[i] = fmaf(b0, r8[i],     accB[i]);
                    accB[i] = fmaf(b1, r8[i + 1], accB[i]);
                    accB[i] = fmaf(b2, r8[i + 2], accB[i]);
                }
            }
        }
    }

    // BN + PReLU -> t_tile
    {
        float iv0 = bninv[ocg],      bb0 = bnbias[ocg],      c0 = cb[ocg];
        float iv1 = bninv[ocg + 16], bb1 = bnbias[ocg + 16], c1 = cb[ocg + 16];
        float al  = alpha_sh;
        #pragma unroll
        for (int i = 0; i < 6; ++i) {
            float v0 = (accA[i] + c0) * iv0 + bb0;
            v0 = (v0 >= 0.f) ? v0 : al * v0;
            t_tile[ocg * 97 + D0 + i] = v0;
            float v1 = (accB[i] + c1) * iv1 + bb1;
            v1 = (v1 >= 0.f) ? v1 : al * v1;
            t_tile[(ocg + 16) * 97 + D0 + i] = v1;
        }
    }
    __syncthreads();

    // logits[b,s,h,w,:] = t . g[s] + h[s]   (offset +1248 past memory_filters)
    long obase = 1248 + (long)b * 13 * 884736 + (long)h * 9216 + (long)w * 96;
    for (int j = tid; j < 13 * 96; j += 256) {
        int s = j / 96;
        int d = j - s * 96;
        float a = h_sh[s];
        const float* gp = &g_sh[s * 32];
        #pragma unroll
        for (int o = 0; o < 32; ++o)
            a = fmaf(t_tile[o * 97 + d], gp[o], a);
        st<FP32>(d_out, obase + (long)s * 884736 + d, a);
    }
}

extern "C" void kernel_launch(void* const* d_in, const int* in_sizes, int n_in,
                              void* d_out, int out_size, void* d_ws, size_t ws_size,
                              hipStream_t stream) {
    const void* y       = d_in[0];
    const void* conv1_w = d_in[1];
    const void* conv1_b = d_in[2];
    const void* bn_g    = d_in[3];
    const void* bn_b    = d_in[4];
    const void* bn_m    = d_in[5];
    const void* bn_v    = d_in[6];
    const void* alpha   = d_in[7];
    const void* conv2_w = d_in[8];
    const void* conv2_b = d_in[9];
    const void* w1      = d_in[10];
    const void* b1      = d_in[11];
    const void* w2      = d_in[12];
    const void* b2      = d_in[13];
    const void* w3      = d_in[14];
    const void* b3      = d_in[15];

    // ws layout (floats): [0..15] flag + pad, [16..431] g (13*32), [432..444] h (13)
    int*   ws_flag = (int*)d_ws;
    float* ws_f    = (float*)d_ws;
    float* ws_g    = ws_f + 16;
    float* ws_h    = ws_f + 16 + 416;

    dtype_probe_kernel<<<1, 64, 0, stream>>>((const unsigned short*)y, ws_flag);

    mlp_kernel<false><<<13, 256, 0, stream>>>(w1, b1, w2, b2, w3, b3, conv2_w, conv2_b,
                                              d_out, ws_g, ws_h, ws_flag);
    mlp_kernel<true ><<<13, 256, 0, stream>>>(w1, b1, w2, b2, w3, b3, conv2_w, conv2_b,
                                              d_out, ws_g, ws_h, ws_flag);

    conv_fused_kernel<false><<<2 * 96 * 96, 256, 0, stream>>>(
        y, conv1_w, conv1_b, bn_g, bn_b, bn_m, bn_v, alpha, ws_g, ws_h, d_out, ws_flag);
    conv_fused_kernel<true ><<<2 * 96 * 96, 256, 0, stream>>>(
        y, conv1_w, conv1_b, bn_g, bn_b, bn_m, bn_v, alpha, ws_g, ws_h, d_out, ws_flag);
}

// Round 2
// 2167.154 us; speedup vs baseline: 1.4150x; 1.2427x over previous
//
#include <hip/hip_runtime.h>
#include <hip/hip_bf16.h>

typedef __hip_bfloat16 bf16;

#define BN_EPS 1e-5f

// ---- dtype-adaptive load/store: FP32=true -> float*, false -> bf16* ----
template<bool FP32>
__device__ __forceinline__ float ld(const void* p, long i) {
    if constexpr (FP32) return ((const float*)p)[i];
    else                return (float)((const bf16*)p)[i];
}
template<bool FP32>
__device__ __forceinline__ void st(void* p, long i, float v) {
    if constexpr (FP32) ((float*)p)[i] = v;
    else                ((bf16*)p)[i] = (bf16)v;
}

// ---------------- dtype probe ----------------
__global__ void dtype_probe_kernel(const unsigned short* __restrict__ y, int* __restrict__ flag)
{
    int tid = threadIdx.x;  // 64 threads
    int mx = 0;
    for (int i = tid; i < 4096; i += 64) {
        int e = (y[i] >> 7) & 0xFF;
        mx = max(mx, e);
    }
    #pragma unroll
    for (int off = 32; off > 0; off >>= 1)
        mx = max(mx, __shfl_down(mx, off, 64));
    if (tid == 0) *flag = (mx >= 141) ? 1 : 0;
}

// ---------------- fused MLP: f -> memory_filters, g, h ----------------
template<bool FP32>
__global__ __launch_bounds__(256) void mlp_kernel(
    const void* __restrict__ w1, const void* __restrict__ b1,
    const void* __restrict__ w2, const void* __restrict__ b2,
    const void* __restrict__ w3, const void* __restrict__ b3,
    const void* __restrict__ c2w, const void* __restrict__ c2b,
    void* __restrict__ d_out,          // memory_filters at offset 0
    float* __restrict__ g_out,         // 13*32
    float* __restrict__ h_out,         // 13
    const int* __restrict__ flag)
{
    if (*flag != (FP32 ? 1 : 0)) return;

    __shared__ float f1[1024];
    __shared__ float f2[2048];
    __shared__ float f3[96];
    __shared__ float fn[96];
    __shared__ float inv_s;

    int s   = blockIdx.x;
    int tid = threadIdx.x;

    // f1 = relu(w1[s,:] + b1)
    for (int j = tid; j < 1024; j += 256)
        f1[j] = fmaxf(ld<FP32>(w1, s * 1024 + j) + ld<FP32>(b1, j), 0.f);
    __syncthreads();

    // f2 = relu(f1 @ w2 + b2)
    {
        float acc[8];
        #pragma unroll
        for (int i = 0; i < 8; ++i) acc[i] = ld<FP32>(b2, tid + 256 * i);
        for (int j = 0; j < 1024; ++j) {
            float a = f1[j];
            long base = (long)j * 2048 + tid;
            #pragma unroll
            for (int i = 0; i < 8; ++i)
                acc[i] = fmaf(a, ld<FP32>(w2, base + 256 * i), acc[i]);
        }
        #pragma unroll
        for (int i = 0; i < 8; ++i) f2[tid + 256 * i] = fmaxf(acc[i], 0.f);
    }
    __syncthreads();

    // f3 = f2 @ w3 + b3
    if (tid < 96) {
        float a0 = 0.f, a1 = 0.f, a2 = 0.f, a3 = 0.f;
        for (int k = 0; k < 2048; k += 4) {
            a0 = fmaf(f2[k],     ld<FP32>(w3, (long)(k)     * 96 + tid), a0);
            a1 = fmaf(f2[k + 1], ld<FP32>(w3, (long)(k + 1) * 96 + tid), a1);
            a2 = fmaf(f2[k + 2], ld<FP32>(w3, (long)(k + 2) * 96 + tid), a2);
            a3 = fmaf(f2[k + 3], ld<FP32>(w3, (long)(k + 3) * 96 + tid), a3);
        }
        f3[tid] = ld<FP32>(b3, tid) + ((a0 + a1) + (a2 + a3));
    }
    __syncthreads();

    if (tid == 0) {
        float ss = 0.f;
        for (int c = 0; c < 96; ++c) ss += f3[c] * f3[c];
        inv_s = 1.f / fmaxf(sqrtf(ss), 1e-12f);
    }
    __syncthreads();

    if (tid < 96) {
        float v = f3[tid] * inv_s;
        fn[tid] = v;
        st<FP32>(d_out, s * 96 + tid, v);   // memory_filters
    }
    __syncthreads();

    // g[s,c] = sum_o fn[o] * conv2_w[o,c];  h[s] = sum_o fn[o] * conv2_b[o]
    if (tid < 32) {
        float g = 0.f;
        #pragma unroll
        for (int o = 0; o < 96; ++o) g = fmaf(fn[o], ld<FP32>(c2w, o * 32 + tid), g);
        g_out[s * 32 + tid] = g;
    } else if (tid == 64) {
        float hv = 0.f;
        for (int o = 0; o < 96; ++o) hv = fmaf(fn[o], ld<FP32>(c2b, o), hv);
        h_out[s] = hv;
    }
}

// ---------------- fused conv1 + BN + PReLU + (g,h) projection -> logits ----------------
// grid = 2*96*48 blocks: one per (b, h, w-pair). Each block produces 2 w positions x 96 d.
// Thread map: ocg = tid&15 -> oc = ocg, ocg+16;  dg = tid>>4 -> 6 consecutive d.
// ic in 8 chunks of 4. y halo rows (3 dz x 4 dy-window x 4 ic = 48 rows) + weights in LDS.
// y_tile aliases t_tile (t only live after the ch loop). LDS ~41.5 KB -> 3 blocks/CU.
template<bool FP32>
__global__ __launch_bounds__(256, 3) void conv_fused_kernel(
    const void* __restrict__ y, const void* __restrict__ w1c, const void* __restrict__ b1c,
    const void* __restrict__ gamma, const void* __restrict__ beta,
    const void* __restrict__ mean,  const void* __restrict__ var,
    const void* __restrict__ alpha_p,
    const float* __restrict__ g_in, const float* __restrict__ h_in,
    void* __restrict__ d_out,
    const int* __restrict__ flag)
{
    if (*flag != (FP32 ? 1 : 0)) return;

    __shared__ float u_buf[6208];          // y_tile: 48 rows x 98  |  t_tile: 2 x 32 x 97
    __shared__ float w_tile[4 * 32 * 28];  // [icl][oc][27] padded to 28
    __shared__ float g_sh[13 * 32];
    __shared__ float h_sh[13];
    __shared__ float bninv[32], bnbias[32], cb[32];
    __shared__ float alpha_sh;
    __shared__ int   row_goff[48];         // per-row global offset (excl. batch/chunk), -1 = OOB

    int tid = threadIdx.x;
    int bid = blockIdx.x;
    int b   = bid / 4608;
    int rem = bid - b * 4608;
    int h   = rem / 48;
    int wp  = rem - h * 48;
    int w0  = wp * 2;

    for (int j = tid; j < 13 * 32; j += 256) g_sh[j] = g_in[j];
    if (tid < 13) h_sh[tid] = h_in[tid];
    if (tid >= 32 && tid < 64) {
        int c = tid - 32;
        float iv = ld<FP32>(gamma, c) * rsqrtf(ld<FP32>(var, c) + BN_EPS);
        bninv[c]  = iv;
        bnbias[c] = ld<FP32>(beta, c) - ld<FP32>(mean, c) * iv;
        cb[c]     = ld<FP32>(b1c, c);
    }
    if (tid == 64) alpha_sh = ld<FP32>(alpha_p, 0);
    if (tid < 48) {
        // row r = dz*16 + dyy*4 + icl
        int dz  = tid >> 4;
        int dyy = (tid >> 2) & 3;
        int icl = tid & 3;
        int hh2 = h + dz - 1;
        int ww2 = w0 + dyy - 1;
        bool ok = ((unsigned)hh2 < 96u) && ((unsigned)ww2 < 96u);
        row_goff[tid] = ok ? (icl * 884736 + hh2 * 9216 + ww2 * 96) : -1;
    }

    int ocg = tid & 15;     // owns oc = ocg, ocg+16
    int dg  = tid >> 4;     // 16 groups of 6 d
    int D0  = dg * 6;
    int wv  = tid >> 6;     // wave id 0..3
    int ln  = tid & 63;     // lane

    float* y_tile = u_buf;

    float accA0[6], accB0[6], accA1[6], accB1[6];
    #pragma unroll
    for (int i = 0; i < 6; ++i) { accA0[i] = 0.f; accB0[i] = 0.f; accA1[i] = 0.f; accB1[i] = 0.f; }

    #pragma unroll 1
    for (int ch = 0; ch < 8; ++ch) {
        __syncthreads();

        // ---- stage 48 y rows: wave per row, lanes cover 98 positions (pos = dd+1) ----
        int bbase = (b * 32 + ch * 4) * 884736;
        for (int r = wv; r < 48; r += 4) {
            float* dst = &y_tile[r * 98];
            int goff = row_goff[r];
            if (goff >= 0) {
                int base = bbase + goff;
                dst[ln] = (ln >= 1) ? ld<FP32>(y, base + (ln - 1)) : 0.f;
                if (ln < 34)
                    dst[ln + 64] = (ln <= 32) ? ld<FP32>(y, base + (ln + 63)) : 0.f;
            } else {
                dst[ln] = 0.f;
                if (ln < 34) dst[ln + 64] = 0.f;
            }
        }

        // ---- stage weights for this 4-ic chunk: 2 threads per (icl,oc) row of 27 ----
        {
            int p    = tid >> 1;          // 0..127 = (icl,oc)
            int half = tid & 1;
            int icl  = p >> 5;
            int oc   = p & 31;
            int t0   = half ? 14 : 0;
            int n    = half ? 13 : 14;
            int gb   = (oc * 32 + (ch * 4 + icl)) * 27 + t0;
            float* dw = &w_tile[(icl * 32 + oc) * 28 + t0];
            for (int q = 0; q < n; ++q) dw[q] = ld<FP32>(w1c, gb + q);
        }
        __syncthreads();

        // ---- compute: 4 ic x 3 dz x 4 dy-window rows; each row feeds w0 and/or w1 ----
        #pragma unroll 1
        for (int icl = 0; icl < 4; ++icl) {
            const float* wpt = &w_tile[(icl * 32 + ocg) * 28];
            float wA[27], wB[27];
            #pragma unroll
            for (int t = 0; t < 27; ++t) { wA[t] = wpt[t]; wB[t] = wpt[16 * 28 + t]; }
            #pragma unroll
            for (int dz = 0; dz < 3; ++dz) {
                #pragma unroll
                for (int dyy = 0; dyy < 4; ++dyy) {
                    const float* row = &y_tile[(dz * 16 + dyy * 4 + icl) * 98 + D0];
                    float r8[8];
                    #pragma unroll
                    for (int q = 0; q < 8; ++q) r8[q] = row[q];
                    if (dyy < 3) {   // contributes to w0 with dy = dyy
                        const int wb = (dz * 3 + dyy) * 3;
                        float a0 = wA[wb], a1 = wA[wb + 1], a2 = wA[wb + 2];
                        float b0 = wB[wb], b1 = wB[wb + 1], b2 = wB[wb + 2];
                        #pragma unroll
                        for (int i = 0; i < 6; ++i) {
                            accA0[i] = fmaf(a0, r8[i],     accA0[i]);
                            accA0[i] = fmaf(a1, r8[i + 1], accA0[i]);
                            accA0[i] = fmaf(a2, r8[i + 2], accA0[i]);
                            accB0[i] = fmaf(b0, r8[i],     accB0[i]);
                            accB0[i] = fmaf(b1, r8[i + 1], accB0[i]);
                            accB0[i] = fmaf(b2, r8[i + 2], accB0[i]);
                        }
                    }
                    if (dyy >= 1) {  // contributes to w1 with dy = dyy-1
                        const int wb = (dz * 3 + dyy - 1) * 3;
                        float a0 = wA[wb], a1 = wA[wb + 1], a2 = wA[wb + 2];
                        float b0 = wB[wb], b1 = wB[wb + 1], b2 = wB[wb + 2];
                        #pragma unroll
                        for (int i = 0; i < 6; ++i) {
                            accA1[i] = fmaf(a0, r8[i],     accA1[i]);
                            accA1[i] = fmaf(a1, r8[i + 1], accA1[i]);
                            accA1[i] = fmaf(a2, r8[i + 2], accA1[i]);
                            accB1[i] = fmaf(b0, r8[i],     accB1[i]);
                            accB1[i] = fmaf(b1, r8[i + 1], accB1[i]);
                            accB1[i] = fmaf(b2, r8[i + 2], accB1[i]);
                        }
                    }
                }
            }
        }
    }

    // all y reads done before t_tile overwrites u_buf
    __syncthreads();

    float* t_tile = u_buf;  // [2][32][97]
    {
        float iv0 = bninv[ocg],      bb0 = bnbias[ocg],      c0 = cb[ocg];
        float iv1 = bninv[ocg + 16], bb1 = bnbias[ocg + 16], c1 = cb[ocg + 16];
        float al  = alpha_sh;
        #pragma unroll
        for (int i = 0; i < 6; ++i) {
            float v;
            v = (accA0[i] + c0) * iv0 + bb0;
            t_tile[ocg * 97 + D0 + i] = (v >= 0.f) ? v : al * v;
            v = (accB0[i] + c1) * iv1 + bb1;
            t_tile[(ocg + 16) * 97 + D0 + i] = (v >= 0.f) ? v : al * v;
            v = (accA1[i] + c0) * iv0 + bb0;
            t_tile[3104 + ocg * 97 + D0 + i] = (v >= 0.f) ? v : al * v;
            v = (accB1[i] + c1) * iv1 + bb1;
            t_tile[3104 + (ocg + 16) * 97 + D0 + i] = (v >= 0.f) ? v : al * v;
        }
    }
    __syncthreads();

    // logits[b,s,h,w0+wsel,:] = t . g[s] + h[s]   (offset +1248 past memory_filters)
    long obase = 1248 + (long)b * 13 * 884736 + (long)h * 9216 + (long)w0 * 96;
    for (int j = tid; j < 2 * 13 * 96; j += 256) {
        int wsel = j / 1248;
        int rem2 = j - wsel * 1248;
        int s = rem2 / 96;
        int d = rem2 - s * 96;
        float a = h_sh[s];
        const float* tp = &t_tile[wsel * 3104];
        const float* gp = &g_sh[s * 32];
        #pragma unroll
        for (int o = 0; o < 32; ++o)
            a = fmaf(tp[o * 97 + d], gp[o], a);
        st<FP32>(d_out, obase + (long)s * 884736 + wsel * 96 + d, a);
    }
}

extern "C" void kernel_launch(void* const* d_in, const int* in_sizes, int n_in,
                              void* d_out, int out_size, void* d_ws, size_t ws_size,
                              hipStream_t stream) {
    const void* y       = d_in[0];
    const void* conv1_w = d_in[1];
    const void* conv1_b = d_in[2];
    const void* bn_g    = d_in[3];
    const void* bn_b    = d_in[4];
    const void* bn_m    = d_in[5];
    const void* bn_v    = d_in[6];
    const void* alpha   = d_in[7];
    const void* conv2_w = d_in[8];
    const void* conv2_b = d_in[9];
    const void* w1      = d_in[10];
    const void* b1      = d_in[11];
    const void* w2      = d_in[12];
    const void* b2      = d_in[13];
    const void* w3      = d_in[14];
    const void* b3      = d_in[15];

    // ws layout (floats): [0..15] flag + pad, [16..431] g (13*32), [432..444] h (13)
    int*   ws_flag = (int*)d_ws;
    float* ws_f    = (float*)d_ws;
    float* ws_g    = ws_f + 16;
    float* ws_h    = ws_f + 16 + 416;

    dtype_probe_kernel<<<1, 64, 0, stream>>>((const unsigned short*)y, ws_flag);

    mlp_kernel<false><<<13, 256, 0, stream>>>(w1, b1, w2, b2, w3, b3, conv2_w, conv2_b,
                                              d_out, ws_g, ws_h, ws_flag);
    mlp_kernel<true ><<<13, 256, 0, stream>>>(w1, b1, w2, b2, w3, b3, conv2_w, conv2_b,
                                              d_out, ws_g, ws_h, ws_flag);

    conv_fused_kernel<false><<<2 * 96 * 48, 256, 0, stream>>>(
        y, conv1_w, conv1_b, bn_g, bn_b, bn_m, bn_v, alpha, ws_g, ws_h, d_out, ws_flag);
    conv_fused_kernel<true ><<<2 * 96 * 48, 256, 0, stream>>>(
        y, conv1_w, conv1_b, bn_g, bn_b, bn_m, bn_v, alpha, ws_g, ws_h, d_out, ws_flag);
}